// Round 3
// baseline (618.191 us; speedup 1.0000x reference)
//
#include <hip/hip_runtime.h>

typedef __bf16  bf16x4 __attribute__((ext_vector_type(4)));
typedef __bf16  bf16x8 __attribute__((ext_vector_type(8)));
typedef float   f32x4  __attribute__((ext_vector_type(4)));
typedef unsigned int u32;

constexpr int BM = 128, BN = 128, BK = 32;

// async global->LDS, 16B per lane. LDS dest is wave-uniform base + lane*16.
__device__ __forceinline__ void async_cp16(const __bf16* g, __bf16* lds) {
    __builtin_amdgcn_global_load_lds(
        (const __attribute__((address_space(1))) u32*)g,
        (__attribute__((address_space(3))) u32*)lds, 16, 0, 0);
}

// swizzled LDS offset (in shorts) of (row, 16B-slot q): conflict-free ds_read_b128
__device__ __forceinline__ int swz(int row, int q) {
    return row * BK + (((q + (row >> 1)) & 3) << 3);
}

// ---------------------------------------------------------------------------
// NT GEMM: C[m,n] = sum_k A[m,k] * Bt[n,k]   (A:[M,K], Bt:[N,K], row-major bf16)
// EPI: 0 = f32 partial (C0+chunk*pstrideB), 1 = bf16 store,
//      2 = +bias,leakyRelu -> bf16, 3 = bf16 partial (C0+chunk*pstrideB),
//      4 = bf16 split across C0/C1/C2 by col/256,
//      5 = fused score epilogue: P'=exp(scale*s - rowtilemax) bf16 -> C0,
//          (max,sumexp) float2 per (row, 128-col tile) -> C1
// CMODE: 0 none, 1 causal tile-skip + diag mask (scores), 2 causal K-limit (PV)
// ALPHA: scale A-fragments by alpha[b][k/128][row] (PV normalization)
// ---------------------------------------------------------------------------
template<int EPI, int CMODE, bool ALPHA>
__launch_bounds__(256)
__global__ void gemm_nt(const __bf16* __restrict__ Aall, const __bf16* __restrict__ Ball,
                        const float* __restrict__ bias, const float* __restrict__ alpha,
                        void* __restrict__ C0, void* __restrict__ C1, void* __restrict__ C2,
                        int N, int K, long sA, long sB, long sC,
                        int nTx, int klen, long pstrideB, float scale)
{
    const int chunk = blockIdx.x / nTx;
    const int n0 = (blockIdx.x - chunk * nTx) * BN;
    const int m0 = blockIdx.y * BM;
    if (CMODE == 1 && n0 >= m0 + BM) return;          // tile above causal diagonal
    const int kbase = chunk * klen;
    int kend = kbase + klen;
    if (CMODE == 2) kend = min(kend, m0 + BM);        // P' is exact 0 for k > q
    const int klocal = kend - kbase;                  // may be <= 0 (writes zeros)

    const __bf16* A  = Aall + (long)blockIdx.z * sA;
    const __bf16* Bt = Ball + (long)blockIdx.z * sB;

    __shared__ alignas(16) __bf16 As[BM * BK];
    __shared__ alignas(16) __bf16 Bs[BN * BK];
    __shared__ float red[2][2][64];                   // cross-wave row reduce (EPI=5)

    const int tid = threadIdx.x;
    const int wave = tid >> 6, lane = tid & 63;
    const int wm = (wave >> 1) * 64, wn = (wave & 1) * 64;
    const int quad = lane >> 4, l16 = lane & 15;

    // staging: 2 rounds x 256 lanes x 16B per matrix; LDS slot u = r*256+tid
    const int row0 = tid >> 2, sl0 = tid & 3;
    const int ks0 = (sl0 - (row0 >> 1)) & 3;
    const int row1 = row0 + 64;
    const int ks1 = (sl0 - (row1 >> 1)) & 3;
    const __bf16* gA0 = A  + (long)(m0 + row0) * K + kbase + ks0 * 8;
    const __bf16* gA1 = A  + (long)(m0 + row1) * K + kbase + ks1 * 8;
    const __bf16* gB0 = Bt + (long)(n0 + row0) * K + kbase + ks0 * 8;
    const __bf16* gB1 = Bt + (long)(n0 + row1) * K + kbase + ks1 * 8;
    __bf16* ldsA0 = As + wave * 512;            // wave-uniform base; lane l -> +l*16B
    __bf16* ldsA1 = As + 2048 + wave * 512;
    __bf16* ldsB0 = Bs + wave * 512;
    __bf16* ldsB1 = Bs + 2048 + wave * 512;

    const float* ap = ALPHA ? (alpha + (long)blockIdx.z * 131072) : nullptr;

    f32x4 acc[4][4];
    #pragma unroll
    for (int i = 0; i < 4; i++)
        #pragma unroll
        for (int j = 0; j < 4; j++) { f32x4 z = {0.f, 0.f, 0.f, 0.f}; acc[i][j] = z; }

    for (int kk = 0; kk < klocal; kk += BK) {
        __syncthreads();                         // prev iter's ds_reads done
        async_cp16(gA0, ldsA0);
        async_cp16(gA1, ldsA1);
        async_cp16(gB0, ldsB0);
        async_cp16(gB1, ldsB1);
        gA0 += BK; gA1 += BK; gB0 += BK; gB1 += BK;
        __syncthreads();                         // vmcnt(0) drain -> LDS populated

        bf16x8 af[4], bg[4];
        #pragma unroll
        for (int i = 0; i < 4; i++) {
            af[i] = *(const bf16x8*)(As + swz(wm + i * 16 + l16, quad));
            bg[i] = *(const bf16x8*)(Bs + swz(wn + i * 16 + l16, quad));
        }
        if (ALPHA) {
            const int ktile = (kbase + kk) >> 7;
            #pragma unroll
            for (int i = 0; i < 4; i++) {
                const float am = ap[(long)ktile * 4096 + m0 + wm + i * 16 + l16];
                #pragma unroll
                for (int jj = 0; jj < 8; jj++)
                    af[i][jj] = (__bf16)((float)af[i][jj] * am);
            }
        }
        #pragma unroll
        for (int i = 0; i < 4; i++)
            #pragma unroll
            for (int j = 0; j < 4; j++)
                acc[i][j] = __builtin_amdgcn_mfma_f32_16x16x32_bf16(af[i], bg[j], acc[i][j], 0, 0, 0);
    }

    if (EPI == 5) {
        // ---- fused partial-softmax epilogue ----
        const bool diag = (CMODE == 1) && (n0 + BM > m0);
        #pragma unroll
        for (int i = 0; i < 4; i++)
            #pragma unroll
            for (int j = 0; j < 4; j++)
                #pragma unroll
                for (int r = 0; r < 4; r++) {
                    float v = acc[i][j][r] * scale;
                    if (diag) {
                        const int grow = m0 + wm + i * 16 + quad * 4 + r;
                        const int gcol = n0 + wn + j * 16 + l16;
                        if (gcol > grow) v = -1e30f;
                    }
                    acc[i][j][r] = v;
                }
        // per-row max over this wave's 64 cols
        float mx[4][4];
        #pragma unroll
        for (int i = 0; i < 4; i++)
            #pragma unroll
            for (int r = 0; r < 4; r++)
                mx[i][r] = fmaxf(fmaxf(acc[i][0][r], acc[i][1][r]),
                                 fmaxf(acc[i][2][r], acc[i][3][r]));
        #pragma unroll
        for (int st = 1; st < 16; st <<= 1)
            #pragma unroll
            for (int i = 0; i < 4; i++)
                #pragma unroll
                for (int r = 0; r < 4; r++)
                    mx[i][r] = fmaxf(mx[i][r], __shfl_xor(mx[i][r], st));
        if (l16 == 0)
            #pragma unroll
            for (int i = 0; i < 4; i++)
                #pragma unroll
                for (int r = 0; r < 4; r++)
                    red[wave >> 1][wave & 1][i * 16 + quad * 4 + r] = mx[i][r];
        __syncthreads();
        #pragma unroll
        for (int i = 0; i < 4; i++)
            #pragma unroll
            for (int r = 0; r < 4; r++)
                mx[i][r] = fmaxf(mx[i][r], red[wave >> 1][(wave & 1) ^ 1][i * 16 + quad * 4 + r]);
        __syncthreads();
        // exp, store P', row sums
        __bf16* sc = (__bf16*)C0 + (long)blockIdx.z * sC;
        float se[4][4];
        #pragma unroll
        for (int i = 0; i < 4; i++)
            #pragma unroll
            for (int r = 0; r < 4; r++) se[i][r] = 0.f;
        #pragma unroll
        for (int i = 0; i < 4; i++)
            #pragma unroll
            for (int j = 0; j < 4; j++)
                #pragma unroll
                for (int r = 0; r < 4; r++) {
                    const float e = __expf(acc[i][j][r] - mx[i][r]);
                    se[i][r] += e;
                    const int grow = m0 + wm + i * 16 + quad * 4 + r;
                    const int gcol = n0 + wn + j * 16 + l16;
                    sc[(long)grow * N + gcol] = (__bf16)e;
                }
        #pragma unroll
        for (int st = 1; st < 16; st <<= 1)
            #pragma unroll
            for (int i = 0; i < 4; i++)
                #pragma unroll
                for (int r = 0; r < 4; r++)
                    se[i][r] += __shfl_xor(se[i][r], st);
        if (l16 == 0)
            #pragma unroll
            for (int i = 0; i < 4; i++)
                #pragma unroll
                for (int r = 0; r < 4; r++)
                    red[wave >> 1][wave & 1][i * 16 + quad * 4 + r] = se[i][r];
        __syncthreads();
        #pragma unroll
        for (int i = 0; i < 4; i++)
            #pragma unroll
            for (int r = 0; r < 4; r++)
                se[i][r] += red[wave >> 1][(wave & 1) ^ 1][i * 16 + quad * 4 + r];
        if ((wave & 1) == 0 && l16 == 0) {
            float2* sideP = (float2*)C1 + (long)blockIdx.z * 131072 + (long)(n0 >> 7) * 4096;
            #pragma unroll
            for (int i = 0; i < 4; i++)
                #pragma unroll
                for (int r = 0; r < 4; r++) {
                    float2 t; t.x = mx[i][r]; t.y = se[i][r];
                    sideP[m0 + wm + i * 16 + quad * 4 + r] = t;
                }
        }
    } else {
        char* cb = (char*)C0 + (long)chunk * pstrideB;
        #pragma unroll
        for (int j = 0; j < 4; j++) {
            const int col = n0 + wn + j * 16 + l16;
            const float bv = (EPI == 2) ? bias[col] : 0.f;
            #pragma unroll
            for (int i = 0; i < 4; i++) {
                #pragma unroll
                for (int r = 0; r < 4; r++) {
                    const int row = m0 + wm + i * 16 + quad * 4 + r;  // C/D: row=(lane>>4)*4+reg
                    float c = acc[i][j][r];
                    if (EPI == 2) { c += bv; c = c > 0.f ? c : 0.2f * c; }
                    if (EPI == 0)
                        ((float*)cb)[(long)blockIdx.z * sC + (long)row * N + col] = c;
                    else if (EPI == 3)
                        ((__bf16*)cb)[(long)blockIdx.z * sC + (long)row * N + col] = (__bf16)c;
                    else if (EPI == 1)
                        ((__bf16*)cb)[(long)blockIdx.z * sC + (long)row * N + col] = (__bf16)c;
                    else if (EPI == 2)
                        ((__bf16*)cb)[(long)row * N + col] = (__bf16)c;
                    else {  // EPI == 4: split by column segment of 256
                        const int seg = col >> 8;
                        __bf16* dst = seg == 0 ? (__bf16*)C0 : (seg == 1 ? (__bf16*)C1 : (__bf16*)C2);
                        dst[(long)row * 256 + (col & 255)] = (__bf16)c;
                    }
                }
            }
        }
    }
}

// side[b][t][row] init to (max=-1e30, sum=0) for causally skipped tiles
__global__ void init_side(float2* __restrict__ s, int n)
{
    const int i = blockIdx.x * 256 + threadIdx.x;
    if (i < n) { float2 t; t.x = -1e30f; t.y = 0.f; s[i] = t; }
}

// per row: gmax/gsum over 32 tiles -> alpha[b][t][row] = exp(m_t-gmax)/gsum
__global__ void reduce_alpha(const float2* __restrict__ side, float* __restrict__ alpha)
{
    const int i = blockIdx.x * 256 + threadIdx.x;     // b*4096 + r
    const int b = i >> 12, r = i & 4095;
    const float2* sp = side + (long)b * 131072 + r;
    float2 v[32];
    float gm = -1e30f;
    #pragma unroll
    for (int t = 0; t < 32; t++) { v[t] = sp[(long)t * 4096]; gm = fmaxf(gm, v[t].x); }
    float gs = 0.f;
    #pragma unroll
    for (int t = 0; t < 32; t++) gs += v[t].y * __expf(v[t].x - gm);
    const float inv = 1.f / gs;
    float* apt = alpha + (long)b * 131072 + r;
    #pragma unroll
    for (int t = 0; t < 32; t++) apt[(long)t * 4096] = __expf(v[t].x - gm) * inv;
}

// (sum of NP bf16 partials) + residual (+ optional col-bias) -> LayerNorm(D=256)
template<int NP>
__launch_bounds__(256)
__global__ void ln_res(const __bf16* __restrict__ p, long pstr,
                       const float* __restrict__ resid, const float* __restrict__ bias,
                       const float* __restrict__ gamma, const float* __restrict__ beta,
                       float* __restrict__ outf, __bf16* __restrict__ outb)
{
    const int row  = blockIdx.x * 4 + (threadIdx.x >> 6);
    const int lane = threadIdx.x & 63;
    const long vi = (long)row * 64 + lane;
    float4 vr = ((const float4*)resid)[vi];
    float x0 = vr.x, x1 = vr.y, x2 = vr.z, x3 = vr.w;
    #pragma unroll
    for (int i = 0; i < NP; i++) {
        bf16x4 vp = ((const bf16x4*)(p + (long)i * pstr))[vi];
        x0 += (float)vp[0]; x1 += (float)vp[1]; x2 += (float)vp[2]; x3 += (float)vp[3];
    }
    if (bias) {
        float4 vb = ((const float4*)bias)[lane];
        x0 += vb.x; x1 += vb.y; x2 += vb.z; x3 += vb.w;
    }
    float s = x0 + x1 + x2 + x3;
    #pragma unroll
    for (int off = 32; off; off >>= 1) s += __shfl_xor(s, off);
    const float mu = s * (1.f / 256.f);
    float d0 = x0 - mu, d1 = x1 - mu, d2 = x2 - mu, d3 = x3 - mu;
    float s2 = d0 * d0 + d1 * d1 + d2 * d2 + d3 * d3;
    #pragma unroll
    for (int off = 32; off; off >>= 1) s2 += __shfl_xor(s2, off);
    const float rs = rsqrtf(s2 * (1.f / 256.f) + 1e-3f);
    const float4 g  = ((const float4*)gamma)[lane];
    const float4 be = ((const float4*)beta)[lane];
    float o0 = d0 * rs * g.x + be.x, o1 = d1 * rs * g.y + be.y;
    float o2 = d2 * rs * g.z + be.z, o3 = d3 * rs * g.w + be.w;
    float4 o; o.x = o0; o.y = o1; o.z = o2; o.w = o3;
    ((float4*)outf)[vi] = o;
    if (outb) {
        bf16x4 ob; ob[0] = (__bf16)o0; ob[1] = (__bf16)o1; ob[2] = (__bf16)o2; ob[3] = (__bf16)o3;
        ((bf16x4*)outb)[vi] = ob;
    }
}

__global__ void f2b4(const float4* __restrict__ in, bf16x4* __restrict__ out, long n4)
{
    long i = (long)blockIdx.x * blockDim.x + threadIdx.x;
    if (i < n4) {
        float4 v = in[i];
        bf16x4 o; o[0] = (__bf16)v.x; o[1] = (__bf16)v.y; o[2] = (__bf16)v.z; o[3] = (__bf16)v.w;
        out[i] = o;
    }
}

__global__ void transpose_pad(const float* __restrict__ src, __bf16* __restrict__ dst,
                              int rows, int cols, int rowsP, int colsP)
{
    int i = blockIdx.x * 256 + threadIdx.x;
    if (i >= rowsP * colsP) return;
    int c = i / rowsP, r = i % rowsP;
    float v = (r < rows && c < cols) ? src[r * cols + c] : 0.f;
    dst[i] = (__bf16)v;
}

__global__ void pad_bias(const float* __restrict__ b, float* __restrict__ bp, int n, int np)
{
    int i = blockIdx.x * 256 + threadIdx.x;
    if (i < np) bp[i] = (i < n) ? b[i] : 0.f;
}

__global__ void transpose_bf(const __bf16* __restrict__ in, __bf16* __restrict__ out,
                             int rows, int cols)
{
    __shared__ __bf16 t[32][33];
    const long base = (long)blockIdx.z * rows * cols;
    const int c0 = blockIdx.x * 32, r0 = blockIdx.y * 32;
    const int tx = threadIdx.x & 31, ty = threadIdx.x >> 5;
    #pragma unroll
    for (int i = 0; i < 32; i += 8)
        t[ty + i][tx] = in[base + (long)(r0 + ty + i) * cols + (c0 + tx)];
    __syncthreads();
    #pragma unroll
    for (int i = 0; i < 32; i += 8)
        out[base + (long)(c0 + ty + i) * rows + (r0 + tx)] = t[tx][ty + i];
}

extern "C" void kernel_launch(void* const* d_in, const int* in_sizes, int n_in,
                              void* d_out, int out_size, void* d_ws, size_t ws_size,
                              hipStream_t stream)
{
    constexpr int B = 4, S = 4096, D = 256, H = 400, Hp = 512;
    constexpr int R = B * S;
    constexpr float SCALE = 1.f / 64.f;   // 1/sqrt(4096)

    const float* inputs = (const float*)d_in[0];
    const float* ctx    = (const float*)d_in[1];
    const float* sa_Wk  = (const float*)d_in[2];
    const float* sa_Wv  = (const float*)d_in[3];
    const float* sa_Wq  = (const float*)d_in[4];
    const float* ca_Wk  = (const float*)d_in[5];
    const float* ca_Wv  = (const float*)d_in[6];
    const float* ca_Wq  = (const float*)d_in[7];
    const float* W1     = (const float*)d_in[8];
    const float* b1     = (const float*)d_in[9];
    const float* W2     = (const float*)d_in[10];
    const float* b2     = (const float*)d_in[11];
    const float* gamma  = (const float*)d_in[12];
    const float* beta   = (const float*)d_in[13];
    float* out = (float*)d_out;

    char* ws = (char*)d_ws;
    size_t off = 0;
    auto alloc = [&](size_t bytes) -> char* {
        char* p = ws + off; off += (bytes + 255) & ~size_t(255); return p;
    };
    __bf16* bfA  = (__bf16*)alloc((size_t)R * D * 2);     // bf16(inputs) -> xbf
    __bf16* bfC  = (__bf16*)alloc((size_t)R * D * 2);     // bf16(context) -> ybf
    __bf16* Qb   = (__bf16*)alloc((size_t)R * D * 2);
    __bf16* Kb   = (__bf16*)alloc((size_t)R * D * 2);
    __bf16* Vt   = (__bf16*)alloc((size_t)B * D * S * 2); // [B][D][S]
    __bf16* h    = (__bf16*)alloc((size_t)R * Hp * 2);    // FFN hidden / Vtmp
    float*  x    = (float*)alloc((size_t)R * D * 4);
    float*  y    = (float*)alloc((size_t)R * D * 4);
    float2* side = (float2*)alloc((size_t)B * 32 * S * 8);   // (max,sum) per (row, ktile)
    float*  alph = (float*)alloc((size_t)B * 32 * S * 4);    // alpha per (row, ktile)
    __bf16* wqkv_s = (__bf16*)alloc((size_t)3 * D * D * 2);  // [Wq^T | Wk^T | Wv^T]
    __bf16* wkv_c  = (__bf16*)alloc((size_t)2 * D * D * 2);  // [Wk^T | Wv^T]
    __bf16* wq_c   = (__bf16*)alloc((size_t)D * D * 2);
    __bf16* W1t  = (__bf16*)alloc((size_t)Hp * D * 2);
    __bf16* W2t  = (__bf16*)alloc((size_t)D * Hp * 2);
    float*  b1p  = (float*)alloc((size_t)Hp * 4);

    const size_t PBb = (size_t)R * D * 2;            // one bf16 partial buffer
    const size_t SCB = (size_t)B * S * S * 2;        // batched exp-scores
    size_t rem = ws_size > off ? ws_size - off : 0;
    int NS;
    if      (rem >= 4 * PBb + SCB) NS = 4;
    else if (rem >= 2 * PBb + SCB) NS = 2;
    else if (rem >= 1 * PBb + SCB) NS = 1;
    else return;                                     // workspace too small
    __bf16* pbuf = (__bf16*)alloc((size_t)NS * PBb);
    __bf16* SC   = (__bf16*)(ws + off);
    const long PBe = (long)R * D;                    // partial stride (elements)

    __bf16* xbf  = bfA;
    __bf16* ybf  = bfC;
    __bf16* Vtmp = h;

    const dim3 blk(256);
    const dim3 gT(D / 32, S / 32, B);

    auto launch_ln = [&](int np, const float* res, const float* bias,
                         float* of, __bf16* ob) {
        if (np == 4)      ln_res<4><<<R / 4, blk, 0, stream>>>(pbuf, PBe, res, bias, gamma, beta, of, ob);
        else if (np == 2) ln_res<2><<<R / 4, blk, 0, stream>>>(pbuf, PBe, res, bias, gamma, beta, of, ob);
        else              ln_res<1><<<R / 4, blk, 0, stream>>>(pbuf, PBe, res, bias, gamma, beta, of, ob);
    };

    // --- prep ---
    f2b4<<<R * D / 1024, blk, 0, stream>>>((const float4*)inputs, (bf16x4*)bfA, (long)R * D / 4);
    f2b4<<<R * D / 1024, blk, 0, stream>>>((const float4*)ctx,    (bf16x4*)bfC, (long)R * D / 4);
    transpose_pad<<<(D * D + 255) / 256, blk, 0, stream>>>(sa_Wq, wqkv_s,             D, D, D, D);
    transpose_pad<<<(D * D + 255) / 256, blk, 0, stream>>>(sa_Wk, wqkv_s + D * D,     D, D, D, D);
    transpose_pad<<<(D * D + 255) / 256, blk, 0, stream>>>(sa_Wv, wqkv_s + 2 * D * D, D, D, D, D);
    transpose_pad<<<(D * D + 255) / 256, blk, 0, stream>>>(ca_Wk, wkv_c,              D, D, D, D);
    transpose_pad<<<(D * D + 255) / 256, blk, 0, stream>>>(ca_Wv, wkv_c + D * D,      D, D, D, D);
    transpose_pad<<<(D * D + 255) / 256, blk, 0, stream>>>(ca_Wq, wq_c,               D, D, D, D);
    transpose_pad<<<(Hp * D + 255) / 256, blk, 0, stream>>>(W1, W1t, D, H, D, Hp);
    transpose_pad<<<(D * Hp + 255) / 256, blk, 0, stream>>>(W2, W2t, H, D, Hp, D);
    pad_bias<<<2, blk, 0, stream>>>(b1, b1p, H, Hp);

    // --- self-attention (causal) ---
    gemm_nt<4, 0, false><<<dim3(6, 128, 1), blk, 0, stream>>>(bfA, wqkv_s, nullptr, nullptr,
        Qb, Kb, Vtmp, 3 * D, D, 0, 0, 0, 6, D, 0, 0.f);
    transpose_bf<<<gT, blk, 0, stream>>>(Vtmp, Vt, S, D);
    init_side<<<(B * 32 * S) / 256, blk, 0, stream>>>(side, B * 32 * S);
    gemm_nt<5, 1, false><<<dim3(32, 32, B), blk, 0, stream>>>(Qb, Kb, nullptr, nullptr,
        SC, side, nullptr, S, D, (long)S * D, (long)S * D, (long)S * S, 32, D, 0, SCALE);
    reduce_alpha<<<(B * S) / 256, blk, 0, stream>>>(side, alph);
    gemm_nt<3, 2, true><<<dim3(2 * NS, 32, B), blk, 0, stream>>>(SC, Vt, nullptr, alph,
        pbuf, nullptr, nullptr, D, S, (long)S * S, (long)D * S, (long)S * D, 2, S / NS, (long)PBb, 0.f);
    launch_ln(NS, inputs, nullptr, x, xbf);

    // --- cross-attention (full): Q from x, fused KV from context ---
    gemm_nt<1, 0, false><<<dim3(2, 128, 1), blk, 0, stream>>>(xbf, wq_c, nullptr, nullptr,
        Qb, nullptr, nullptr, D, D, 0, 0, 0, 2, D, 0, 0.f);
    gemm_nt<4, 0, false><<<dim3(4, 128, 1), blk, 0, stream>>>(bfC, wkv_c, nullptr, nullptr,
        Kb, Vtmp, nullptr, 2 * D, D, 0, 0, 0, 4, D, 0, 0.f);
    transpose_bf<<<gT, blk, 0, stream>>>(Vtmp, Vt, S, D);
    gemm_nt<5, 0, false><<<dim3(32, 32, B), blk, 0, stream>>>(Qb, Kb, nullptr, nullptr,
        SC, side, nullptr, S, D, (long)S * D, (long)S * D, (long)S * S, 32, D, 0, SCALE);
    reduce_alpha<<<(B * S) / 256, blk, 0, stream>>>(side, alph);
    gemm_nt<3, 0, true><<<dim3(2 * NS, 32, B), blk, 0, stream>>>(SC, Vt, nullptr, alph,
        pbuf, nullptr, nullptr, D, S, (long)S * S, (long)D * S, (long)S * D, 2, S / NS, (long)PBb, 0.f);
    launch_ln(NS, x, nullptr, y, ybf);

    // --- FFN ---
    gemm_nt<2, 0, false><<<dim3(4, 128, 1), blk, 0, stream>>>(ybf, W1t, b1p, nullptr,
        h, nullptr, nullptr, Hp, D, 0, 0, 0, 4, D, 0, 0.f);
    gemm_nt<3, 0, false><<<dim3(2 * NS, 128, 1), blk, 0, stream>>>(h, W2t, nullptr, nullptr,
        pbuf, nullptr, nullptr, D, Hp, 0, 0, 0, 2, Hp / NS, (long)PBb, 0.f);
    launch_ln(NS, y, b2, out, nullptr);   // b2 folded into pre-LN sum
}